// Round 1
// baseline (61.237 us; speedup 1.0000x reference)
//
#include <hip/hip_runtime.h>

// Volume renderer: one ray per wave (64 lanes). Samples are distributed
// lane-parallel in chunks of 64; the sequential alpha-blend is an ordered
// associative fold of affine maps f(x) = a*x + b, reduced with a butterfly.

__global__ __launch_bounds__(256) void volrend_kernel(
    const float* __restrict__ W,      // [128,128,128,28]
    const float* __restrict__ rays,   // [N,6]
    float* __restrict__ out,          // [N,4]
    int N)
{
    const int lane = threadIdx.x & 63;
    const int ray  = (int)((blockIdx.x * blockDim.x + threadIdx.x) >> 6);
    if (ray >= N) return;

    const float ox = rays[ray*6+0];
    const float oy = rays[ray*6+1];
    const float oz = rays[ray*6+2];
    const float rx = rays[ray*6+3];
    const float ry = rays[ray*6+4];
    const float rz = rays[ray*6+5];

    // d = d_raw / ||d_raw||  (exact sqrt + division, matches reference)
    const float nrm = sqrtf(rx*rx + ry*ry + rz*rz);
    const float dx = rx/nrm, dy = ry/nrm, dz = rz/nrm;

    // ray-AABB, box [-1.5, 1.5]^3
    const float ivx = 1.0f/dx, ivy = 1.0f/dy, ivz = 1.0f/dz;
    const float t0x = (-1.5f-ox)*ivx, t1x = (1.5f-ox)*ivx;
    const float t0y = (-1.5f-oy)*ivy, t1y = (1.5f-oy)*ivy;
    const float t0z = (-1.5f-oz)*ivz, t1z = (1.5f-oz)*ivz;
    const float tmin = fmaxf(fmaxf(fminf(t0x,t1x), fminf(t0y,t1y)), fminf(t0z,t1z));
    const float tmax = fminf(fminf(fmaxf(t0x,t1x), fmaxf(t0y,t1y)), fmaxf(t0z,t1z));
    const float tnear = fmaxf(tmin, 0.0f);
    const bool  isect = (tmax >= tnear);
    const float span  = tmax - tnear;

    const int   ns  = isect ? (int)fminf(span*32.0f, 256.0f) : 0;
    const float nsf = (float)(ns > 1 ? ns : 1);
    const float dist = span / nsf;

    // SH basis from RAW direction (reference uses d_raw, not normalized d)
    const float b1=rx, b2=ry, b3=rz, b4=rx*ry, b5=rx*rz, b6=ry*rz, b7=rx*rx, b8=ry*ry;

    // running composite over samples [0, base):  x -> RA*x + RB_c
    float RA = 1.0f, RB0 = 0.0f, RB1 = 0.0f, RB2 = 0.0f, RB3 = 0.0f;

    for (int base = 0; base < ns; base += 64) {
        const int j = base + lane;
        // per-sample affine map (identity for invalid lanes)
        float A = 1.0f, B0 = 0.0f, B1 = 0.0f, B2 = 0.0f, B3 = 0.0f;
        if (j < ns) {
            const float t  = tnear + (span * ((float)j + 0.5f)) / nsf;
            const float px = ((ox + dx*t) / 1.5f) * 0.5f + 0.5f;
            const float py = ((oy + dy*t) / 1.5f) * 0.5f + 0.5f;
            const float pz = ((oz + dz*t) / 1.5f) * 0.5f + 0.5f;
            int ix = (int)floorf(px * 128.0f); ix = ix < 0 ? 0 : (ix > 127 ? 127 : ix);
            int iy = (int)floorf(py * 128.0f); iy = iy < 0 ? 0 : (iy > 127 ? 127 : iy);
            int iz = (int)floorf(pz * 128.0f); iz = iz < 0 ? 0 : (iz > 127 ? 127 : iz);
            const int vox = ((ix*128 + iy)*128 + iz);
            const float4* p = reinterpret_cast<const float4*>(W + (size_t)vox * 28);
            const float4 q0 = p[0], q1 = p[1], q2 = p[2], q3 = p[3],
                         q4 = p[4], q5 = p[5], q6 = p[6];
            // sh[c][k] = param[c*9+k], sigma = param[27]
            const float rgb0 = q0.x      + q0.y*b1 + q0.z*b2 + q0.w*b3 +
                               q1.x*b4   + q1.y*b5 + q1.z*b6 + q1.w*b7 + q2.x*b8;
            const float rgb1 = q2.y      + q2.z*b1 + q2.w*b2 + q3.x*b3 +
                               q3.y*b4   + q3.z*b5 + q3.w*b6 + q4.x*b7 + q4.y*b8;
            const float rgb2 = q4.z      + q4.w*b1 + q5.x*b2 + q5.y*b3 +
                               q5.z*b4   + q5.w*b5 + q6.x*b6 + q6.y*b7 + q6.z*b8;
            const float sg = q6.w;
            const float a  = 1.0f - expf(sg * dist);
            const float om = 1.0f - a;
            A = a;
            B0 = rgb0*om; B1 = rgb1*om; B2 = rgb2*om; B3 = sg*om;
        }

        // ordered butterfly reduce of the 64 affine maps of this chunk.
        // After the loop every lane holds compose(f_{base+63} ... f_{base}).
        #pragma unroll
        for (int off = 1; off < 64; off <<= 1) {
            const float Ao = __shfl_xor(A,  off);
            const float C0 = __shfl_xor(B0, off);
            const float C1 = __shfl_xor(B1, off);
            const float C2 = __shfl_xor(B2, off);
            const float C3 = __shfl_xor(B3, off);
            const bool lower = (lane & off) == 0;  // my segment comes first
            const float nB0 = lower ? B0*Ao + C0 : C0*A + B0;
            const float nB1 = lower ? B1*Ao + C1 : C1*A + B1;
            const float nB2 = lower ? B2*Ao + C2 : C2*A + B2;
            const float nB3 = lower ? B3*Ao + C3 : C3*A + B3;
            A  = A * Ao;
            B0 = nB0; B1 = nB1; B2 = nB2; B3 = nB3;
        }

        // running = chunk ∘ running
        RB0 = RB0*A + B0;
        RB1 = RB1*A + B1;
        RB2 = RB2*A + B2;
        RB3 = RB3*A + B3;
        RA  = RA * A;
    }

    if (lane == 0) {
        // color0 = ones -> color_c = RA*1 + RB_c
        float4 col;
        col.x = RA + RB0;
        col.y = RA + RB1;
        col.z = RA + RB2;
        col.w = RA + RB3;
        *reinterpret_cast<float4*>(out + (size_t)ray * 4) = col;
    }
}

extern "C" void kernel_launch(void* const* d_in, const int* in_sizes, int n_in,
                              void* d_out, int out_size, void* d_ws, size_t ws_size,
                              hipStream_t stream) {
    const float* W    = (const float*)d_in[0];   // 128^3 * 28 floats
    const float* rays = (const float*)d_in[1];   // [N,6]
    float* out        = (float*)d_out;           // [N,4]
    const int N = in_sizes[1] / 6;               // 16384

    const int threads = 256;                     // 4 waves = 4 rays per block
    const int blocks  = (N * 64 + threads - 1) / threads;
    volrend_kernel<<<blocks, threads, 0, stream>>>(W, rays, out, N);
}

// Round 2
// 59.741 us; speedup vs baseline: 1.0250x; 1.0250x over previous
//
#include <hip/hip_runtime.h>

// Volume renderer: one ray per wave (64 lanes). Samples are distributed
// lane-parallel in chunks of 64; the sequential alpha-blend is an ordered
// associative fold of affine maps f(x) = a*x + b, reduced with a butterfly.
// Chunk k+1's gathers are issued before chunk k is consumed (depth-1
// software pipeline) so each wave keeps 7 loads in flight during compute.

__global__ __launch_bounds__(256) void volrend_kernel(
    const float* __restrict__ W,      // [128,128,128,28]
    const float* __restrict__ rays,   // [N,6]
    float* __restrict__ out,          // [N,4]
    int N)
{
    const int lane = threadIdx.x & 63;
    int ray = (int)((blockIdx.x * blockDim.x + threadIdx.x) >> 6);
    ray = __builtin_amdgcn_readfirstlane(ray);   // wave-uniform -> SGPR
    if (ray >= N) return;

    const float ox = rays[ray*6+0];
    const float oy = rays[ray*6+1];
    const float oz = rays[ray*6+2];
    const float rx = rays[ray*6+3];
    const float ry = rays[ray*6+4];
    const float rz = rays[ray*6+5];

    // d = d_raw / ||d_raw||  (exact sqrt + division, matches reference)
    const float nrm = sqrtf(rx*rx + ry*ry + rz*rz);
    const float dx = rx/nrm, dy = ry/nrm, dz = rz/nrm;

    // ray-AABB, box [-1.5, 1.5]^3
    const float ivx = 1.0f/dx, ivy = 1.0f/dy, ivz = 1.0f/dz;
    const float t0x = (-1.5f-ox)*ivx, t1x = (1.5f-ox)*ivx;
    const float t0y = (-1.5f-oy)*ivy, t1y = (1.5f-oy)*ivy;
    const float t0z = (-1.5f-oz)*ivz, t1z = (1.5f-oz)*ivz;
    const float tmin = fmaxf(fmaxf(fminf(t0x,t1x), fminf(t0y,t1y)), fminf(t0z,t1z));
    const float tmax = fminf(fminf(fmaxf(t0x,t1x), fmaxf(t0y,t1y)), fmaxf(t0z,t1z));
    const float tnear = fmaxf(tmin, 0.0f);
    const bool  isect = (tmax >= tnear);
    const float span  = tmax - tnear;

    const int   ns  = isect ? (int)fminf(span*32.0f, 256.0f) : 0;
    const float nsf = (float)(ns > 1 ? ns : 1);
    const float inv_nsf = 1.0f / nsf;       // one divide per ray
    const float dist = span * inv_nsf;

    // SH basis from RAW direction (reference uses d_raw, not normalized d)
    const float b1=rx, b2=ry, b3=rz, b4=rx*ry, b5=rx*rz, b6=ry*rz, b7=rx*rx, b8=ry*ry;

    // running composite over processed samples:  x -> RA*x + RB_c
    float RA = 1.0f, RB0 = 0.0f, RB1 = 0.0f, RB2 = 0.0f, RB3 = 0.0f;

    // ---- prologue: issue chunk-0 gathers ----
    float4 cur[7];
    bool curv;
    {
        const int j = lane;
        curv = (j < ns);
        if (curv) {
            const float t  = tnear + span * ((float)j + 0.5f) * inv_nsf;
            const float px = ((ox + dx*t) / 1.5f) * 0.5f + 0.5f;
            const float py = ((oy + dy*t) / 1.5f) * 0.5f + 0.5f;
            const float pz = ((oz + dz*t) / 1.5f) * 0.5f + 0.5f;
            int ix = (int)floorf(px * 128.0f); ix = ix < 0 ? 0 : (ix > 127 ? 127 : ix);
            int iy = (int)floorf(py * 128.0f); iy = iy < 0 ? 0 : (iy > 127 ? 127 : iy);
            int iz = (int)floorf(pz * 128.0f); iz = iz < 0 ? 0 : (iz > 127 ? 127 : iz);
            const float4* p = reinterpret_cast<const float4*>(W + (size_t)((ix*128 + iy)*128 + iz) * 28);
            #pragma unroll
            for (int k = 0; k < 7; ++k) cur[k] = p[k];
        }
    }

    for (int base = 0; base < ns; base += 64) {
        // ---- prefetch chunk k+1 while chunk k is still in flight ----
        float4 nxt[7];
        const int jn = base + 64 + lane;
        const bool nxtv = (jn < ns);
        if (nxtv) {
            const float t  = tnear + span * ((float)jn + 0.5f) * inv_nsf;
            const float px = ((ox + dx*t) / 1.5f) * 0.5f + 0.5f;
            const float py = ((oy + dy*t) / 1.5f) * 0.5f + 0.5f;
            const float pz = ((oz + dz*t) / 1.5f) * 0.5f + 0.5f;
            int ix = (int)floorf(px * 128.0f); ix = ix < 0 ? 0 : (ix > 127 ? 127 : ix);
            int iy = (int)floorf(py * 128.0f); iy = iy < 0 ? 0 : (iy > 127 ? 127 : iy);
            int iz = (int)floorf(pz * 128.0f); iz = iz < 0 ? 0 : (iz > 127 ? 127 : iz);
            const float4* p = reinterpret_cast<const float4*>(W + (size_t)((ix*128 + iy)*128 + iz) * 28);
            #pragma unroll
            for (int k = 0; k < 7; ++k) nxt[k] = p[k];
        }

        // ---- consume chunk k ----
        float A = 1.0f, B0 = 0.0f, B1 = 0.0f, B2 = 0.0f, B3 = 0.0f;
        if (curv) {
            const float4 q0 = cur[0], q1 = cur[1], q2 = cur[2], q3 = cur[3],
                         q4 = cur[4], q5 = cur[5], q6 = cur[6];
            const float rgb0 = q0.x      + q0.y*b1 + q0.z*b2 + q0.w*b3 +
                               q1.x*b4   + q1.y*b5 + q1.z*b6 + q1.w*b7 + q2.x*b8;
            const float rgb1 = q2.y      + q2.z*b1 + q2.w*b2 + q3.x*b3 +
                               q3.y*b4   + q3.z*b5 + q3.w*b6 + q4.x*b7 + q4.y*b8;
            const float rgb2 = q4.z      + q4.w*b1 + q5.x*b2 + q5.y*b3 +
                               q5.z*b4   + q5.w*b5 + q6.x*b6 + q6.y*b7 + q6.z*b8;
            const float sg = q6.w;
            const float a  = 1.0f - __expf(sg * dist);
            const float om = 1.0f - a;
            A = a;
            B0 = rgb0*om; B1 = rgb1*om; B2 = rgb2*om; B3 = sg*om;
        }

        // ordered butterfly reduce of the 64 affine maps of this chunk.
        #pragma unroll
        for (int off = 1; off < 64; off <<= 1) {
            const float Ao = __shfl_xor(A,  off);
            const float C0 = __shfl_xor(B0, off);
            const float C1 = __shfl_xor(B1, off);
            const float C2 = __shfl_xor(B2, off);
            const float C3 = __shfl_xor(B3, off);
            const bool lower = (lane & off) == 0;  // my segment comes first
            const float nB0 = lower ? B0*Ao + C0 : C0*A + B0;
            const float nB1 = lower ? B1*Ao + C1 : C1*A + B1;
            const float nB2 = lower ? B2*Ao + C2 : C2*A + B2;
            const float nB3 = lower ? B3*Ao + C3 : C3*A + B3;
            A  = A * Ao;
            B0 = nB0; B1 = nB1; B2 = nB2; B3 = nB3;
        }

        // running = chunk ∘ running
        RB0 = RB0*A + B0;
        RB1 = RB1*A + B1;
        RB2 = RB2*A + B2;
        RB3 = RB3*A + B3;
        RA  = RA * A;

        // rotate pipeline
        #pragma unroll
        for (int k = 0; k < 7; ++k) cur[k] = nxt[k];
        curv = nxtv;
    }

    if (lane == 0) {
        // color0 = ones -> color_c = RA*1 + RB_c
        float4 col;
        col.x = RA + RB0;
        col.y = RA + RB1;
        col.z = RA + RB2;
        col.w = RA + RB3;
        *reinterpret_cast<float4*>(out + (size_t)ray * 4) = col;
    }
}

extern "C" void kernel_launch(void* const* d_in, const int* in_sizes, int n_in,
                              void* d_out, int out_size, void* d_ws, size_t ws_size,
                              hipStream_t stream) {
    const float* W    = (const float*)d_in[0];   // 128^3 * 28 floats
    const float* rays = (const float*)d_in[1];   // [N,6]
    float* out        = (float*)d_out;           // [N,4]
    const int N = in_sizes[1] / 6;               // 16384

    const int threads = 256;                     // 4 waves = 4 rays per block
    const int blocks  = (N * 64 + threads - 1) / threads;
    volrend_kernel<<<blocks, threads, 0, stream>>>(W, rays, out, N);
}